// Round 1
// baseline (581.955 us; speedup 1.0000x reference)
//
#include <hip/hip_runtime.h>

// B=8 S=1024 D=1024 H=16 DH=64.
// Head bh=b*16+s_hi (s_hi=s>>6); head elem (p,f) -> proj[b][s_hi*64+(p>>4)][(p&15)*64+f].
// mask index for head bh is s_hi&7. scale=0.5.

typedef unsigned short u16;
typedef __attribute__((ext_vector_type(8))) short bf16x8;
typedef __attribute__((ext_vector_type(4))) float f32x4;

#define MFMA_BF16(a, b, c) __builtin_amdgcn_mfma_f32_16x16x32_bf16((a), (b), (c), 0, 0, 0)

__device__ __forceinline__ u16 f2bf(float f) {
  unsigned u = __float_as_uint(f);
  u += 0x7fffu + ((u >> 16) & 1u);   // round-nearest-even
  return (u16)(u >> 16);
}

static constexpr size_t MD = 8192ull * 1024ull;  // one [B,S,D] tensor, elements
static constexpr size_t DD = 1024ull * 1024ull;  // one [D,D] weight, elements

// ---------------- f32 -> bf16 for key/value/query ----------------
__global__ __launch_bounds__(256) void cvt_k(const float* __restrict__ K,
                                             const float* __restrict__ V,
                                             const float* __restrict__ Q,
                                             u16* __restrict__ O) {
  const int z = blockIdx.z;
  const float* src = (z == 0) ? K : ((z == 1) ? V : Q);
  const size_t i = ((size_t)blockIdx.x * 256 + threadIdx.x) * 4;
  const float4 v = *reinterpret_cast<const float4*>(src + i);
  ushort4 o;
  o.x = f2bf(v.x); o.y = f2bf(v.y); o.z = f2bf(v.z); o.w = f2bf(v.w);
  *reinterpret_cast<ushort4*>(O + (size_t)z * MD + i) = o;
}

// ---------------- W[K,N] f32 -> WT[N,K] bf16, for Wk,Wv,Wq,Wf ----------------
__global__ __launch_bounds__(256) void wt_k(const float* __restrict__ Wk,
                                            const float* __restrict__ Wv,
                                            const float* __restrict__ Wq,
                                            const float* __restrict__ Wf,
                                            u16* __restrict__ WT) {
  const int z = blockIdx.z;
  const float* W = (z == 0) ? Wk : ((z == 1) ? Wv : ((z == 2) ? Wq : Wf));
  __shared__ float tile[32][33];
  const int k0 = blockIdx.y * 32, n0 = blockIdx.x * 32;
  const int r = threadIdx.x >> 5, c = threadIdx.x & 31;
#pragma unroll
  for (int rr = r; rr < 32; rr += 8)
    tile[rr][c] = W[(size_t)(k0 + rr) * 1024 + n0 + c];
  __syncthreads();
#pragma unroll
  for (int rr = r; rr < 32; rr += 8)
    WT[(size_t)z * DD + (size_t)(n0 + rr) * 1024 + k0 + c] = f2bf(tile[c][rr]);
}

// ---------------- GEMM: C[M,N] = A[M,K] * BT[N,K]^T (+bias, epilogues) -------
// EPI==0: C -> bf16 (projections, z=0,1,2). EPI==1: C+resid -> f32 (final).
template <int EPI>
__global__ __launch_bounds__(256) void gemm_bt(
    const u16* __restrict__ A0, const u16* __restrict__ B0,
    const float* __restrict__ bias0, const float* __restrict__ bias1,
    const float* __restrict__ bias2, u16* __restrict__ Obf,
    float* __restrict__ Of, const float* __restrict__ resid) {
  __shared__ __align__(16) u16 As[128][40];  // +8 pad: conflict-spread, 16B rows
  __shared__ __align__(16) u16 Bs[128][40];
  const int z = blockIdx.z;
  const u16* A = A0 + (size_t)z * MD;
  const u16* Bt = B0 + (size_t)z * DD;
  const float* bias = (z == 0) ? bias0 : ((z == 1) ? bias1 : bias2);
  const int t = threadIdx.x;
  const int m0 = blockIdx.y * 128, n0 = blockIdx.x * 128;
  const int w = t >> 6, lane = t & 63, lr = lane & 15, lk = lane >> 4;
  const int wm = (w >> 1) * 64, wn = (w & 1) * 64;
  const int srow = t >> 2, scol = (t & 3) * 8;

  f32x4 acc[4][4] = {};

  for (int k0 = 0; k0 < 1024; k0 += 32) {
    const int4 a0 = *reinterpret_cast<const int4*>(A + (size_t)(m0 + srow) * 1024 + k0 + scol);
    const int4 a1 = *reinterpret_cast<const int4*>(A + (size_t)(m0 + srow + 64) * 1024 + k0 + scol);
    const int4 b0 = *reinterpret_cast<const int4*>(Bt + (size_t)(n0 + srow) * 1024 + k0 + scol);
    const int4 b1 = *reinterpret_cast<const int4*>(Bt + (size_t)(n0 + srow + 64) * 1024 + k0 + scol);
    __syncthreads();  // previous iter's fragment reads done before overwrite
    *reinterpret_cast<int4*>(&As[srow][scol]) = a0;
    *reinterpret_cast<int4*>(&As[srow + 64][scol]) = a1;
    *reinterpret_cast<int4*>(&Bs[srow][scol]) = b0;
    *reinterpret_cast<int4*>(&Bs[srow + 64][scol]) = b1;
    __syncthreads();
    bf16x8 af[4], bfr[4];
#pragma unroll
    for (int i = 0; i < 4; ++i)
      af[i] = *reinterpret_cast<const bf16x8*>(&As[wm + i * 16 + lr][lk * 8]);
#pragma unroll
    for (int j = 0; j < 4; ++j)
      bfr[j] = *reinterpret_cast<const bf16x8*>(&Bs[wn + j * 16 + lr][lk * 8]);
#pragma unroll
    for (int i = 0; i < 4; ++i) {
#pragma unroll
      for (int j = 0; j < 4; ++j)
        acc[i][j] = MFMA_BF16(af[i], bfr[j], acc[i][j]);
    }
  }

#pragma unroll
  for (int i = 0; i < 4; ++i) {
#pragma unroll
    for (int j = 0; j < 4; ++j) {
#pragma unroll
      for (int r = 0; r < 4; ++r) {
        const int row = m0 + wm + i * 16 + lk * 4 + r;  // C/D: row=(lane>>4)*4+reg
        const int col = n0 + wn + j * 16 + lr;          //       col=lane&15
        const float v = acc[i][j][r] + bias[col];
        if constexpr (EPI == 0) {
          Obf[(size_t)z * MD + (size_t)row * 1024 + col] = f2bf(v);
        } else {
          const size_t idx = (size_t)row * 1024 + col;
          Of[idx] = v + resid[idx];
        }
      }
    }
  }
}

// ---------------- V head-transpose: Vt[bh][f][p'] bf16 ----------------
__global__ __launch_bounds__(256) void vt_k(const u16* __restrict__ VP,
                                            u16* __restrict__ VTo) {
  __shared__ __align__(16) u16 tile[64][72];
  const int t = threadIdx.x;
  const int bh = blockIdx.y, p0 = blockIdx.x * 64;
  const int b = bh >> 4, shi = bh & 15;
  const size_t hb = (size_t)b * 1048576 + (size_t)shi * 65536;
#pragma unroll
  for (int it = 0; it < 2; ++it) {
    const int c = t + it * 256;
    const int row = c >> 3, f8 = (c & 7) * 8;
    const int p = p0 + row;
    *reinterpret_cast<int4*>(&tile[row][f8]) = *reinterpret_cast<const int4*>(
        VP + hb + (size_t)(p >> 4) * 1024 + (p & 15) * 64 + f8);
  }
  __syncthreads();
#pragma unroll
  for (int it = 0; it < 2; ++it) {
    const int c = t + it * 256;
    const int f = c >> 3, pc = (c & 7) * 8;
    __align__(16) u16 tmp[8];
#pragma unroll
    for (int i = 0; i < 8; ++i) tmp[i] = tile[pc + i][f];
    *reinterpret_cast<int4*>(VTo + (size_t)bh * 65536 + (size_t)f * 1024 + p0 + pc) =
        *reinterpret_cast<int4*>(tmp);
  }
}

// ---------------- fused attention ----------------
// Block = (q-tile of 64 rows) x (head bh). 4 waves, wave w owns q-rows w*16..+15.
// Pass A: row sums of exp(0.5*QK^T) under mask (no max-subtract; scores <= ~15).
// Pass B: recompute, normalize, write probs f32 to d_out, accumulate P@V via LDS.
__global__ __launch_bounds__(256) void attn_k(
    const u16* __restrict__ QP, const u16* __restrict__ KP,
    const u16* __restrict__ VT, const unsigned char* __restrict__ mask8,
    float* __restrict__ attnOut, u16* __restrict__ ctx) {
  __shared__ __align__(16) u16 Qs[64][72];
  __shared__ __align__(16) u16 Ks[64][72];
  __shared__ __align__(16) u16 Vs[64][72];   // Vs[f][p'_local]
  __shared__ __align__(16) u16 Ps[4][16][72];
  __shared__ int mflag;

  const int t = threadIdx.x;
  const int bh = blockIdx.y;
  const int q0 = blockIdx.x * 64;
  const int b = bh >> 4, shi = bh & 15;
  const size_t hb = (size_t)b * 1048576 + (size_t)shi * 65536;
  const size_t mbase = (size_t)(shi & 7) * 1048576;

  // mask storage-layout detection: 0=u8(bool), 1=int32, 2=float32
  if (t == 0) {
    const unsigned* mw = reinterpret_cast<const unsigned*>(mask8);
    int allI = 1, allF = 1;
    for (int i = 0; i < 64; ++i) {
      const unsigned v = mw[i];
      if (v != 0u && v != 1u) allI = 0;
      if (v != 0u && v != 0x3F800000u) allF = 0;
    }
    mflag = allI ? 1 : (allF ? 2 : 0);
  }
#pragma unroll
  for (int it = 0; it < 2; ++it) {
    const int c = t + it * 256;
    const int row = c >> 3, f8 = (c & 7) * 8;
    const int p = q0 + row;
    *reinterpret_cast<int4*>(&Qs[row][f8]) = *reinterpret_cast<const int4*>(
        QP + hb + (size_t)(p >> 4) * 1024 + (p & 15) * 64 + f8);
  }
  __syncthreads();

  const int w = t >> 6, lane = t & 63, lr = lane & 15, lk = lane >> 4;
  const int mmode = mflag;
  const bf16x8 qf0 = *reinterpret_cast<const bf16x8*>(&Qs[w * 16 + lr][lk * 8]);
  const bf16x8 qf1 = *reinterpret_cast<const bf16x8*>(&Qs[w * 16 + lr][32 + lk * 8]);

  float part[4] = {0.f, 0.f, 0.f, 0.f};

  // ---- pass A: exp row-sums ----
  for (int kt = 0; kt < 16; ++kt) {
    __syncthreads();
#pragma unroll
    for (int it = 0; it < 2; ++it) {
      const int c = t + it * 256;
      const int row = c >> 3, f8 = (c & 7) * 8;
      const int p = kt * 64 + row;
      *reinterpret_cast<int4*>(&Ks[row][f8]) = *reinterpret_cast<const int4*>(
          KP + hb + (size_t)(p >> 4) * 1024 + (p & 15) * 64 + f8);
    }
    __syncthreads();
    f32x4 sf[4] = {};
#pragma unroll
    for (int j = 0; j < 4; ++j) {
      const bf16x8 k0f = *reinterpret_cast<const bf16x8*>(&Ks[j * 16 + lr][lk * 8]);
      sf[j] = MFMA_BF16(qf0, k0f, sf[j]);
      const bf16x8 k1f = *reinterpret_cast<const bf16x8*>(&Ks[j * 16 + lr][32 + lk * 8]);
      sf[j] = MFMA_BF16(qf1, k1f, sf[j]);
    }
#pragma unroll
    for (int j = 0; j < 4; ++j) {
      const int col = kt * 64 + j * 16 + lr;
#pragma unroll
      for (int r = 0; r < 4; ++r) {
        const int qrow = q0 + w * 16 + lk * 4 + r;
        const size_t mi = mbase + (size_t)qrow * 1024 + col;
        const unsigned char m =
            (mmode == 0) ? mask8[mi] : ((mmode == 1) ? mask8[mi * 4] : mask8[mi * 4 + 3]);
        part[r] += m ? 0.f : __expf(0.5f * sf[j][r]);
      }
    }
  }
  float rinv[4];
#pragma unroll
  for (int r = 0; r < 4; ++r) {
    float v = part[r];
    v += __shfl_xor(v, 1, 64); v += __shfl_xor(v, 2, 64);
    v += __shfl_xor(v, 4, 64); v += __shfl_xor(v, 8, 64);
    rinv[r] = (v > 0.f) ? (1.f / v) : 0.f;
  }

  // ---- pass B: normalize, emit probs, accumulate P@V ----
  f32x4 cacc[4] = {};
  for (int kt = 0; kt < 16; ++kt) {
    __syncthreads();
#pragma unroll
    for (int it = 0; it < 2; ++it) {
      const int c = t + it * 256;
      const int row = c >> 3, f8 = (c & 7) * 8;
      const int p = kt * 64 + row;
      *reinterpret_cast<int4*>(&Ks[row][f8]) = *reinterpret_cast<const int4*>(
          KP + hb + (size_t)(p >> 4) * 1024 + (p & 15) * 64 + f8);
      *reinterpret_cast<int4*>(&Vs[row][f8]) = *reinterpret_cast<const int4*>(
          VT + (size_t)bh * 65536 + (size_t)row * 1024 + kt * 64 + f8);
    }
    __syncthreads();
    f32x4 sf[4] = {};
#pragma unroll
    for (int j = 0; j < 4; ++j) {
      const bf16x8 k0f = *reinterpret_cast<const bf16x8*>(&Ks[j * 16 + lr][lk * 8]);
      sf[j] = MFMA_BF16(qf0, k0f, sf[j]);
      const bf16x8 k1f = *reinterpret_cast<const bf16x8*>(&Ks[j * 16 + lr][32 + lk * 8]);
      sf[j] = MFMA_BF16(qf1, k1f, sf[j]);
    }
#pragma unroll
    for (int j = 0; j < 4; ++j) {
      const int col = kt * 64 + j * 16 + lr;
#pragma unroll
      for (int r = 0; r < 4; ++r) {
        const int qrow = q0 + w * 16 + lk * 4 + r;
        const size_t mi = mbase + (size_t)qrow * 1024 + col;
        const unsigned char m =
            (mmode == 0) ? mask8[mi] : ((mmode == 1) ? mask8[mi * 4] : mask8[mi * 4 + 3]);
        float pv = m ? 0.f : __expf(0.5f * sf[j][r]);
        pv *= rinv[r];
        attnOut[(size_t)bh * 1048576 + (size_t)qrow * 1024 + col] = pv;
        Ps[w][lk * 4 + r][j * 16 + lr] = f2bf(pv);
      }
    }
    __syncthreads();  // Ps visible (and Ks/Vs stable) before PV MFMAs
#pragma unroll
    for (int c = 0; c < 2; ++c) {
      const bf16x8 pf = *reinterpret_cast<const bf16x8*>(&Ps[w][lr][c * 32 + lk * 8]);
#pragma unroll
      for (int j2 = 0; j2 < 4; ++j2) {
        const bf16x8 vf = *reinterpret_cast<const bf16x8*>(&Vs[j2 * 16 + lr][c * 32 + lk * 8]);
        cacc[j2] = MFMA_BF16(pf, vf, cacc[j2]);
      }
    }
  }
#pragma unroll
  for (int j2 = 0; j2 < 4; ++j2) {
#pragma unroll
    for (int r = 0; r < 4; ++r) {
      const int p = q0 + w * 16 + lk * 4 + r;
      const int f = j2 * 16 + lr;
      ctx[hb + (size_t)(p >> 4) * 1024 + (p & 15) * 64 + f] = f2bf(cacc[j2][r]);
    }
  }
}

// ---------------- LayerNorm over last dim (1024) ----------------
__global__ __launch_bounds__(256) void ln_k(const float* __restrict__ X,
                                            const float* __restrict__ gamma,
                                            const float* __restrict__ beta,
                                            float* __restrict__ Y) {
  const int row = blockIdx.x, t = threadIdx.x;
  const size_t base = (size_t)row * 1024;
  const float4 x = *reinterpret_cast<const float4*>(X + base + t * 4);
  float s = x.x + x.y + x.z + x.w;
  float s2 = x.x * x.x + x.y * x.y + x.z * x.z + x.w * x.w;
#pragma unroll
  for (int d = 1; d < 64; d <<= 1) {
    s += __shfl_xor(s, d, 64);
    s2 += __shfl_xor(s2, d, 64);
  }
  __shared__ float red[8];
  const int w = t >> 6;
  if ((t & 63) == 0) { red[w] = s; red[4 + w] = s2; }
  __syncthreads();
  s = red[0] + red[1] + red[2] + red[3];
  s2 = red[4] + red[5] + red[6] + red[7];
  const float mu = s * (1.f / 1024.f);
  const float var = s2 * (1.f / 1024.f) - mu * mu;
  const float inv = rsqrtf(var + 1e-5f);
  const float4 g = *reinterpret_cast<const float4*>(gamma + t * 4);
  const float4 be = *reinterpret_cast<const float4*>(beta + t * 4);
  float4 y;
  y.x = (x.x - mu) * inv * g.x + be.x;
  y.y = (x.y - mu) * inv * g.y + be.y;
  y.z = (x.z - mu) * inv * g.z + be.z;
  y.w = (x.w - mu) * inv * g.w + be.w;
  *reinterpret_cast<float4*>(Y + base + t * 4) = y;
}

extern "C" void kernel_launch(void* const* d_in, const int* in_sizes, int n_in,
                              void* d_out, int out_size, void* d_ws, size_t ws_size,
                              hipStream_t stream) {
  const float* keyF = (const float*)d_in[0];
  const float* valueF = (const float*)d_in[1];
  const float* queryF = (const float*)d_in[2];
  const unsigned char* mask8 = (const unsigned char*)d_in[3];
  const float* Wk = (const float*)d_in[4];
  const float* bk = (const float*)d_in[5];
  const float* Wv = (const float*)d_in[6];
  const float* bv = (const float*)d_in[7];
  const float* Wq = (const float*)d_in[8];
  const float* bq = (const float*)d_in[9];
  const float* Wf = (const float*)d_in[10];
  const float* bfp = (const float*)d_in[11];
  const float* gamma = (const float*)d_in[12];
  const float* beta = (const float*)d_in[13];

  char* ws = (char*)d_ws;
  // layout (bytes): [0,48M) Xbf k/v/q bf16 | [48M,56M) WT x4 | [56M,104M) K/V/Q proj
  // | [104M,120M) Vt. After projections: [0,16M) ctx (reuse), [16M,48M) preLN f32.
  u16* Xbf = (u16*)(ws);
  u16* WT = (u16*)(ws + 50331648);
  u16* KP = (u16*)(ws + 58720256);
  u16* VP = (u16*)(ws + 75497472);
  u16* QP = (u16*)(ws + 92274688);
  u16* VT = (u16*)(ws + 109051904);
  u16* CTX = (u16*)(ws);
  float* PRELN = (float*)(ws + 16777216);

  float* outF = (float*)d_out;
  float* attnF = outF + 8388608;

  cvt_k<<<dim3(8192, 1, 3), 256, 0, stream>>>(keyF, valueF, queryF, Xbf);
  wt_k<<<dim3(32, 32, 4), 256, 0, stream>>>(Wk, Wv, Wq, Wf, WT);
  gemm_bt<0><<<dim3(8, 64, 3), 256, 0, stream>>>(Xbf, WT, bk, bv, bq, KP, nullptr, nullptr);
  vt_k<<<dim3(16, 128), 256, 0, stream>>>(VP, VT);
  attn_k<<<dim3(16, 128), 256, 0, stream>>>(QP, KP, VT, mask8, attnF, CTX);
  gemm_bt<1><<<dim3(8, 64, 1), 256, 0, stream>>>(CTX, WT + 3 * DD, bfp, bfp, bfp,
                                                 nullptr, PRELN, queryF);
  ln_k<<<dim3(8192), 256, 0, stream>>>(PRELN, gamma, beta, outF);
}

// Round 2
// 437.686 us; speedup vs baseline: 1.3296x; 1.3296x over previous
//
#include <hip/hip_runtime.h>

// B=8 S=1024 D=1024 H=16 DH=64.
// Head bh=b*16+s_hi (s_hi=s>>6); head elem (p,f) -> proj[b][s_hi*64+(p>>4)][(p&15)*64+f].
// mask index for head bh is s_hi&7. scale=0.5 (=> exp2 domain: 0.5*log2e).

typedef unsigned short u16;
typedef unsigned long long u64;
typedef __attribute__((ext_vector_type(8))) short bf16x8;
typedef __attribute__((ext_vector_type(4))) float f32x4;

#define MFMA_BF16(a, b, c) __builtin_amdgcn_mfma_f32_16x16x32_bf16((a), (b), (c), 0, 0, 0)

__device__ __forceinline__ u16 f2bf(float f) {
  unsigned u = __float_as_uint(f);
  u += 0x7fffu + ((u >> 16) & 1u);   // round-nearest-even
  return (u16)(u >> 16);
}

static constexpr size_t MD = 8192ull * 1024ull;  // one [B,S,D] tensor, elements
static constexpr size_t DD = 1024ull * 1024ull;  // one [D,D] weight, elements
static constexpr float SCL = 0.72134752044f;     // 0.5 * log2(e)

// ---------------- f32 -> bf16 for key/value/query ----------------
__global__ __launch_bounds__(256) void cvt_k(const float* __restrict__ K,
                                             const float* __restrict__ V,
                                             const float* __restrict__ Q,
                                             u16* __restrict__ O) {
  const int z = blockIdx.z;
  const float* src = (z == 0) ? K : ((z == 1) ? V : Q);
  const size_t i = ((size_t)blockIdx.x * 256 + threadIdx.x) * 4;
  const float4 v = *reinterpret_cast<const float4*>(src + i);
  ushort4 o;
  o.x = f2bf(v.x); o.y = f2bf(v.y); o.z = f2bf(v.z); o.w = f2bf(v.w);
  *reinterpret_cast<ushort4*>(O + (size_t)z * MD + i) = o;
}

// ---------------- W[K,N] f32 -> WT[N,K] bf16, for Wk,Wv,Wq,Wf ----------------
__global__ __launch_bounds__(256) void wt_k(const float* __restrict__ Wk,
                                            const float* __restrict__ Wv,
                                            const float* __restrict__ Wq,
                                            const float* __restrict__ Wf,
                                            u16* __restrict__ WT) {
  const int z = blockIdx.z;
  const float* W = (z == 0) ? Wk : ((z == 1) ? Wv : ((z == 2) ? Wq : Wf));
  __shared__ float tile[32][33];
  const int k0 = blockIdx.y * 32, n0 = blockIdx.x * 32;
  const int r = threadIdx.x >> 5, c = threadIdx.x & 31;
#pragma unroll
  for (int rr = r; rr < 32; rr += 8)
    tile[rr][c] = W[(size_t)(k0 + rr) * 1024 + n0 + c];
  __syncthreads();
#pragma unroll
  for (int rr = r; rr < 32; rr += 8)
    WT[(size_t)z * DD + (size_t)(n0 + rr) * 1024 + k0 + c] = f2bf(tile[c][rr]);
}

// ---------------- mask -> bit-packed u64 words: mb[8][1024][16] ----------------
// Word w of row r of mask m covers cols w*64..w*64+63; bit c = mask nonzero.
__global__ __launch_bounds__(256) void mb_k(const unsigned char* __restrict__ mask8,
                                            u64* __restrict__ mb) {
  __shared__ int mflag;
  if (threadIdx.x == 0) {
    const unsigned* mw = reinterpret_cast<const unsigned*>(mask8);
    int allW = 1;  // storage is 4-byte words (int32 0/1 or f32 0.0/1.0)?
    for (int i = 0; i < 64; ++i) {
      const unsigned v = mw[i];
      if (v != 0u && v != 1u && v != 0x3F800000u) allW = 0;
    }
    mflag = allW;
  }
  __syncthreads();
  const int wide = mflag;
  const size_t wi = (size_t)blockIdx.x * 256 + threadIdx.x;  // word index
  const size_t src0 = wi * 64;                               // first element idx
  u64 bits = 0ull;
  if (!wide) {  // u8 bool storage
    const uint4* p = reinterpret_cast<const uint4*>(mask8 + src0);
#pragma unroll
    for (int q = 0; q < 4; ++q) {
      const uint4 v = p[q];
      const unsigned vv[4] = {v.x, v.y, v.z, v.w};
#pragma unroll
      for (int k = 0; k < 4; ++k) {
        unsigned tt = vv[k];
        tt |= tt >> 4; tt |= tt >> 2; tt |= tt >> 1;
        tt &= 0x01010101u;
        const unsigned nib =
            (tt & 1u) | ((tt >> 7) & 2u) | ((tt >> 14) & 4u) | ((tt >> 21) & 8u);
        bits |= (u64)nib << (q * 16 + k * 4);
      }
    }
  } else {  // 4-byte storage: nonzero word => masked
    const unsigned* p = reinterpret_cast<const unsigned*>(mask8) + src0;
#pragma unroll
    for (int k = 0; k < 64; ++k)
      bits |= (u64)(p[k] != 0u) << k;
  }
  mb[wi] = bits;
}

// ---------------- GEMM: C[M,N] = A[M,K] * BT[N,K]^T (+bias, epilogues) -------
// EPI==0: C -> bf16 (projections, z=0,1,2). EPI==1: C+resid -> f32 (final).
template <int EPI>
__global__ __launch_bounds__(256) void gemm_bt(
    const u16* __restrict__ A0, const u16* __restrict__ B0,
    const float* __restrict__ bias0, const float* __restrict__ bias1,
    const float* __restrict__ bias2, u16* __restrict__ Obf,
    float* __restrict__ Of, const float* __restrict__ resid) {
  __shared__ __align__(16) u16 As[128][40];  // +8 pad: conflict-spread, 16B rows
  __shared__ __align__(16) u16 Bs[128][40];
  const int z = blockIdx.z;
  const u16* A = A0 + (size_t)z * MD;
  const u16* Bt = B0 + (size_t)z * DD;
  const float* bias = (z == 0) ? bias0 : ((z == 1) ? bias1 : bias2);
  const int t = threadIdx.x;
  const int m0 = blockIdx.y * 128, n0 = blockIdx.x * 128;
  const int w = t >> 6, lane = t & 63, lr = lane & 15, lk = lane >> 4;
  const int wm = (w >> 1) * 64, wn = (w & 1) * 64;
  const int srow = t >> 2, scol = (t & 3) * 8;

  f32x4 acc[4][4] = {};

  for (int k0 = 0; k0 < 1024; k0 += 32) {
    const int4 a0 = *reinterpret_cast<const int4*>(A + (size_t)(m0 + srow) * 1024 + k0 + scol);
    const int4 a1 = *reinterpret_cast<const int4*>(A + (size_t)(m0 + srow + 64) * 1024 + k0 + scol);
    const int4 b0 = *reinterpret_cast<const int4*>(Bt + (size_t)(n0 + srow) * 1024 + k0 + scol);
    const int4 b1 = *reinterpret_cast<const int4*>(Bt + (size_t)(n0 + srow + 64) * 1024 + k0 + scol);
    __syncthreads();  // previous iter's fragment reads done before overwrite
    *reinterpret_cast<int4*>(&As[srow][scol]) = a0;
    *reinterpret_cast<int4*>(&As[srow + 64][scol]) = a1;
    *reinterpret_cast<int4*>(&Bs[srow][scol]) = b0;
    *reinterpret_cast<int4*>(&Bs[srow + 64][scol]) = b1;
    __syncthreads();
    bf16x8 af[4], bfr[4];
#pragma unroll
    for (int i = 0; i < 4; ++i)
      af[i] = *reinterpret_cast<const bf16x8*>(&As[wm + i * 16 + lr][lk * 8]);
#pragma unroll
    for (int j = 0; j < 4; ++j)
      bfr[j] = *reinterpret_cast<const bf16x8*>(&Bs[wn + j * 16 + lr][lk * 8]);
#pragma unroll
    for (int i = 0; i < 4; ++i) {
#pragma unroll
      for (int j = 0; j < 4; ++j)
        acc[i][j] = MFMA_BF16(af[i], bfr[j], acc[i][j]);
    }
  }

#pragma unroll
  for (int i = 0; i < 4; ++i) {
#pragma unroll
    for (int j = 0; j < 4; ++j) {
#pragma unroll
      for (int r = 0; r < 4; ++r) {
        const int row = m0 + wm + i * 16 + lk * 4 + r;  // C/D: row=(lane>>4)*4+reg
        const int col = n0 + wn + j * 16 + lr;          //       col=lane&15
        const float v = acc[i][j][r] + bias[col];
        if constexpr (EPI == 0) {
          Obf[(size_t)z * MD + (size_t)row * 1024 + col] = f2bf(v);
        } else {
          const size_t idx = (size_t)row * 1024 + col;
          Of[idx] = v + resid[idx];
        }
      }
    }
  }
}

// ---------------- V head-transpose: Vt[bh][f][p'] bf16 ----------------
__global__ __launch_bounds__(256) void vt_k(const u16* __restrict__ VP,
                                            u16* __restrict__ VTo) {
  __shared__ __align__(16) u16 tile[64][72];
  const int t = threadIdx.x;
  const int bh = blockIdx.y, p0 = blockIdx.x * 64;
  const int b = bh >> 4, shi = bh & 15;
  const size_t hb = (size_t)b * 1048576 + (size_t)shi * 65536;
#pragma unroll
  for (int it = 0; it < 2; ++it) {
    const int c = t + it * 256;
    const int row = c >> 3, f8 = (c & 7) * 8;
    const int p = p0 + row;
    *reinterpret_cast<int4*>(&tile[row][f8]) = *reinterpret_cast<const int4*>(
        VP + hb + (size_t)(p >> 4) * 1024 + (p & 15) * 64 + f8);
  }
  __syncthreads();
#pragma unroll
  for (int it = 0; it < 2; ++it) {
    const int c = t + it * 256;
    const int f = c >> 3, pc = (c & 7) * 8;
    __align__(16) u16 tmp[8];
#pragma unroll
    for (int i = 0; i < 8; ++i) tmp[i] = tile[pc + i][f];
    *reinterpret_cast<int4*>(VTo + (size_t)bh * 65536 + (size_t)f * 1024 + p0 + pc) =
        *reinterpret_cast<int4*>(tmp);
  }
}

// ---------------- fused attention ----------------
// Grid (128, 16): bh = blockIdx.x (XCD-local head), q0 = blockIdx.y*64.
// 4 waves, wave w owns q-rows w*16..+15.
// Pass A: row sums of exp2(SCL*QK^T) under bitmask (no max-subtract; |scores| small).
// Pass B: recompute, p = exp2(fma(s,SCL, log2(rinv) or -inf)), write probs, P@V.
__global__ __launch_bounds__(256) void attn_k(
    const u16* __restrict__ QP, const u16* __restrict__ KP,
    const u16* __restrict__ VT, const u64* __restrict__ mb,
    float* __restrict__ attnOut, u16* __restrict__ ctx) {
  __shared__ __align__(16) u16 Qs[64][72];
  __shared__ __align__(16) u16 Ks[64][72];
  __shared__ __align__(16) u16 Vs[64][72];       // Vs[f][p'_local]
  __shared__ __align__(16) u16 Ps[4][16][76];    // pad 76: conflict-free wr/rd

  const int t = threadIdx.x;
  const int bh = blockIdx.x;
  const int q0 = blockIdx.y * 64;
  const int b = bh >> 4, shi = bh & 15;
  const size_t hb = (size_t)b * 1048576 + (size_t)shi * 65536;
  const u64* mrow = mb + (size_t)(shi & 7) * 16384;  // [1024][16] words

#pragma unroll
  for (int it = 0; it < 2; ++it) {
    const int c = t + it * 256;
    const int row = c >> 3, f8 = (c & 7) * 8;
    const int p = q0 + row;
    *reinterpret_cast<int4*>(&Qs[row][f8]) = *reinterpret_cast<const int4*>(
        QP + hb + (size_t)(p >> 4) * 1024 + (p & 15) * 64 + f8);
  }
  __syncthreads();

  const int w = t >> 6, lane = t & 63, lr = lane & 15, lk = lane >> 4;
  const bf16x8 qf0 = *reinterpret_cast<const bf16x8*>(&Qs[w * 16 + lr][lk * 8]);
  const bf16x8 qf1 = *reinterpret_cast<const bf16x8*>(&Qs[w * 16 + lr][32 + lk * 8]);
  const int qr0 = q0 + w * 16 + lk * 4;  // this thread's 4 score rows

  float part[4] = {0.f, 0.f, 0.f, 0.f};

  // ---- pass A: exp2 row-sums ----
  for (int kt = 0; kt < 16; ++kt) {
    __syncthreads();
#pragma unroll
    for (int it = 0; it < 2; ++it) {
      const int c = t + it * 256;
      const int row = c >> 3, f8 = (c & 7) * 8;
      const int p = kt * 64 + row;
      *reinterpret_cast<int4*>(&Ks[row][f8]) = *reinterpret_cast<const int4*>(
          KP + hb + (size_t)(p >> 4) * 1024 + (p & 15) * 64 + f8);
    }
    __syncthreads();
    f32x4 sf[4] = {};
#pragma unroll
    for (int j = 0; j < 4; ++j) {
      const bf16x8 k0f = *reinterpret_cast<const bf16x8*>(&Ks[j * 16 + lr][lk * 8]);
      sf[j] = MFMA_BF16(qf0, k0f, sf[j]);
      const bf16x8 k1f = *reinterpret_cast<const bf16x8*>(&Ks[j * 16 + lr][32 + lk * 8]);
      sf[j] = MFMA_BF16(qf1, k1f, sf[j]);
    }
    u64 sh[4];
#pragma unroll
    for (int r = 0; r < 4; ++r) sh[r] = mrow[(size_t)(qr0 + r) * 16 + kt] >> lr;
#pragma unroll
    for (int j = 0; j < 4; ++j) {
#pragma unroll
      for (int r = 0; r < 4; ++r) {
        const unsigned bit = (unsigned)(sh[r] >> (j * 16)) & 1u;
        const float sel = bit ? -__builtin_inff() : 0.0f;
        part[r] += __builtin_amdgcn_exp2f(fmaf(sf[j][r], SCL, sel));
      }
    }
  }
  float l2r[4];
#pragma unroll
  for (int r = 0; r < 4; ++r) {
    float v = part[r];
    v += __shfl_xor(v, 1, 64); v += __shfl_xor(v, 2, 64);
    v += __shfl_xor(v, 4, 64); v += __shfl_xor(v, 8, 64);
    l2r[r] = (v > 0.f) ? -__builtin_amdgcn_logf(v) : -__builtin_inff();
  }

  // ---- pass B: p = exp2(fma(s,SCL, l2r|-inf)), emit probs, accumulate P@V ----
  f32x4 cacc[4] = {};
  for (int kt = 0; kt < 16; ++kt) {
    __syncthreads();
#pragma unroll
    for (int it = 0; it < 2; ++it) {
      const int c = t + it * 256;
      const int row = c >> 3, f8 = (c & 7) * 8;
      const int p = kt * 64 + row;
      *reinterpret_cast<int4*>(&Ks[row][f8]) = *reinterpret_cast<const int4*>(
          KP + hb + (size_t)(p >> 4) * 1024 + (p & 15) * 64 + f8);
      *reinterpret_cast<int4*>(&Vs[row][f8]) = *reinterpret_cast<const int4*>(
          VT + (size_t)bh * 65536 + (size_t)row * 1024 + kt * 64 + f8);
    }
    __syncthreads();
    f32x4 sf[4] = {};
#pragma unroll
    for (int j = 0; j < 4; ++j) {
      const bf16x8 k0f = *reinterpret_cast<const bf16x8*>(&Ks[j * 16 + lr][lk * 8]);
      sf[j] = MFMA_BF16(qf0, k0f, sf[j]);
      const bf16x8 k1f = *reinterpret_cast<const bf16x8*>(&Ks[j * 16 + lr][32 + lk * 8]);
      sf[j] = MFMA_BF16(qf1, k1f, sf[j]);
    }
    u64 sh[4];
#pragma unroll
    for (int r = 0; r < 4; ++r) sh[r] = mrow[(size_t)(qr0 + r) * 16 + kt] >> lr;
#pragma unroll
    for (int j = 0; j < 4; ++j) {
#pragma unroll
      for (int r = 0; r < 4; ++r) {
        const unsigned bit = (unsigned)(sh[r] >> (j * 16)) & 1u;
        const float sel = bit ? -__builtin_inff() : l2r[r];
        const float pv = __builtin_amdgcn_exp2f(fmaf(sf[j][r], SCL, sel));
        attnOut[(size_t)bh * 1048576 + (size_t)(qr0 + r) * 1024 + kt * 64 + j * 16 + lr] = pv;
        Ps[w][lk * 4 + r][j * 16 + lr] = f2bf(pv);
      }
    }
    // Ps is wave-private (written+read by wave w only): no barrier needed.
#pragma unroll
    for (int c = 0; c < 2; ++c) {
      const bf16x8 pf = *reinterpret_cast<const bf16x8*>(&Ps[w][lr][c * 32 + lk * 8]);
#pragma unroll
      for (int j2 = 0; j2 < 4; ++j2) {
        const bf16x8 vf = *reinterpret_cast<const bf16x8*>(&Vs[j2 * 16 + lr][c * 32 + lk * 8]);
        cacc[j2] = MFMA_BF16(pf, vf, cacc[j2]);
      }
    }
  }
#pragma unroll
  for (int j2 = 0; j2 < 4; ++j2) {
#pragma unroll
    for (int r = 0; r < 4; ++r) {
      const int p = q0 + w * 16 + lk * 4 + r;
      const int f = j2 * 16 + lr;
      ctx[hb + (size_t)(p >> 4) * 1024 + (p & 15) * 64 + f] = f2bf(cacc[j2][r]);
    }
  }
}

// ---------------- LayerNorm over last dim (1024) ----------------
__global__ __launch_bounds__(256) void ln_k(const float* __restrict__ X,
                                            const float* __restrict__ gamma,
                                            const float* __restrict__ beta,
                                            float* __restrict__ Y) {
  const int row = blockIdx.x, t = threadIdx.x;
  const size_t base = (size_t)row * 1024;
  const float4 x = *reinterpret_cast<const float4*>(X + base + t * 4);
  float s = x.x + x.y + x.z + x.w;
  float s2 = x.x * x.x + x.y * x.y + x.z * x.z + x.w * x.w;
#pragma unroll
  for (int d = 1; d < 64; d <<= 1) {
    s += __shfl_xor(s, d, 64);
    s2 += __shfl_xor(s2, d, 64);
  }
  __shared__ float red[8];
  const int w = t >> 6;
  if ((t & 63) == 0) { red[w] = s; red[4 + w] = s2; }
  __syncthreads();
  s = red[0] + red[1] + red[2] + red[3];
  s2 = red[4] + red[5] + red[6] + red[7];
  const float mu = s * (1.f / 1024.f);
  const float var = s2 * (1.f / 1024.f) - mu * mu;
  const float inv = rsqrtf(var + 1e-5f);
  const float4 g = *reinterpret_cast<const float4*>(gamma + t * 4);
  const float4 be = *reinterpret_cast<const float4*>(beta + t * 4);
  float4 y;
  y.x = (x.x - mu) * inv * g.x + be.x;
  y.y = (x.y - mu) * inv * g.y + be.y;
  y.z = (x.z - mu) * inv * g.z + be.z;
  y.w = (x.w - mu) * inv * g.w + be.w;
  *reinterpret_cast<float4*>(Y + base + t * 4) = y;
}

extern "C" void kernel_launch(void* const* d_in, const int* in_sizes, int n_in,
                              void* d_out, int out_size, void* d_ws, size_t ws_size,
                              hipStream_t stream) {
  const float* keyF = (const float*)d_in[0];
  const float* valueF = (const float*)d_in[1];
  const float* queryF = (const float*)d_in[2];
  const unsigned char* mask8 = (const unsigned char*)d_in[3];
  const float* Wk = (const float*)d_in[4];
  const float* bk = (const float*)d_in[5];
  const float* Wv = (const float*)d_in[6];
  const float* bv = (const float*)d_in[7];
  const float* Wq = (const float*)d_in[8];
  const float* bq = (const float*)d_in[9];
  const float* Wf = (const float*)d_in[10];
  const float* bfp = (const float*)d_in[11];
  const float* gamma = (const float*)d_in[12];
  const float* beta = (const float*)d_in[13];

  char* ws = (char*)d_ws;
  // layout (bytes): [0,48M) Xbf k/v/q bf16 | [48M,56M) WT x4 | [56M,104M) K/V/Q proj
  // | [104M,120M) Vt | [120M,121M) mask bits. After projections: [0,16M) ctx,
  // [16M,48M) preLN f32.
  u16* Xbf = (u16*)(ws);
  u16* WT = (u16*)(ws + 50331648);
  u16* KP = (u16*)(ws + 58720256);
  u16* VP = (u16*)(ws + 75497472);
  u16* QP = (u16*)(ws + 92274688);
  u16* VT = (u16*)(ws + 109051904);
  u64* MB = (u64*)(ws + 125829120);
  u16* CTX = (u16*)(ws);
  float* PRELN = (float*)(ws + 16777216);

  float* outF = (float*)d_out;
  float* attnF = outF + 8388608;

  cvt_k<<<dim3(8192, 1, 3), 256, 0, stream>>>(keyF, valueF, queryF, Xbf);
  wt_k<<<dim3(32, 32, 4), 256, 0, stream>>>(Wk, Wv, Wq, Wf, WT);
  mb_k<<<dim3(512), 256, 0, stream>>>(mask8, MB);
  gemm_bt<0><<<dim3(8, 64, 3), 256, 0, stream>>>(Xbf, WT, bk, bv, bq, KP, nullptr, nullptr);
  vt_k<<<dim3(16, 128), 256, 0, stream>>>(VP, VT);
  attn_k<<<dim3(128, 16), 256, 0, stream>>>(QP, KP, VT, MB, attnF, CTX);
  gemm_bt<1><<<dim3(8, 64, 1), 256, 0, stream>>>(CTX, WT + 3 * DD, bfp, bfp, bfp,
                                                 nullptr, PRELN, queryF);
  ln_k<<<dim3(8192), 256, 0, stream>>>(PRELN, gamma, beta, outF);
}